// Round 6
// baseline (273.514 us; speedup 1.0000x reference)
//
#include <hip/hip_runtime.h>
#include <math.h>

// Problem constants (fixed-shape problem)
#define B_  16
#define D_  37
#define F_  4096
#define I_  64
#define EPS 1e-5f
// softmax scale 1/sqrt(64) folded with log2(e) into q at projection time,
// so S_mfma = att*log2e and softmax is a raw exp2. |att|<=8 (LN rows have
// norm exactly 8) -> exp2(S) <= 2^11.6: no max pass, bf16-safe unnormalized P.
#define QSCALE 0.18033688011112042f
#define NQS 2           // stats q-split (partial-Z planes)

typedef unsigned short u16;
typedef __bf16 bf16x8 __attribute__((ext_vector_type(8)));
typedef __bf16 bf16x2v __attribute__((ext_vector_type(2)));
typedef float  f32x16 __attribute__((ext_vector_type(16)));
typedef float  f32x2v __attribute__((ext_vector_type(2)));
typedef unsigned int u32x4 __attribute__((ext_vector_type(4)));
typedef int i32x2 __attribute__((ext_vector_type(2)));

#define ZERO16 {0,0,0,0, 0,0,0,0, 0,0,0,0, 0,0,0,0}
#define MFMA32(a, b, c) __builtin_amdgcn_mfma_f32_32x32x16_bf16((a), (b), (c), 0, 0, 0)

#if __has_builtin(__builtin_amdgcn_exp2f)
#define EX2(x) __builtin_amdgcn_exp2f(x)
#else
#define EX2(x) exp2f(x)
#endif
#if __has_builtin(__builtin_amdgcn_rcpf)
#define RCP(x) __builtin_amdgcn_rcpf(x)
#else
#define RCP(x) (1.f / (x))
#endif

// fp32 -> bf16 RNE (scalar, for qkv/vscale)
__device__ __forceinline__ u16 f2b(float f) {
  unsigned u = __builtin_bit_cast(unsigned, f);
  return (u16)((u + 0x7fffu + ((u >> 16) & 1u)) >> 16);
}
// pack two fp32 -> bf16x2 (one v_cvt_pk_bf16_f32 where available)
__device__ __forceinline__ unsigned pk2(float lo, float hi) {
  f32x2v f = {lo, hi};
  bf16x2v h = __builtin_convertvector(f, bf16x2v);
  return __builtin_bit_cast(unsigned, h);
}

// half-wave register swap (v_permlane32_swap_b32 on gfx950)
__device__ __forceinline__ void plswap(unsigned& a, unsigned& b) {
#if __has_builtin(__builtin_amdgcn_permlane32_swap)
  i32x2 r = __builtin_amdgcn_permlane32_swap((int)a, (int)b, false, false);
  a = (unsigned)r[0];
  b = (unsigned)r[1];
#else
  const int lh = (int)((threadIdx.x & 63) >> 5);
  unsigned pa = (unsigned)__shfl_xor((int)a, 32, 64);
  unsigned pb = (unsigned)__shfl_xor((int)b, 32, 64);
  unsigned na = lh ? pb : a;
  unsigned nb = lh ? b : pa;
  a = na;
  b = nb;
#endif
}

// From one S^T 32x32 C-block (rows=k, cols=q), build two PV A-fragments
// (m=q, contraction k): f0 = k 0..15, f1 = k 16..31 of this block.
// C-reg r holds k=(r&3)+8*(r>>2)+4*lh; A-frag VGPR j needs k=lh*8+2j(+1).
__device__ __forceinline__ void build_af(const f32x16& s, bf16x8& f0, bf16x8& f1) {
  float e[16];
#pragma unroll
  for (int r = 0; r < 16; ++r) e[r] = EX2(s[r]);
  unsigned a = pk2(e[0], e[1]),   bq = pk2(e[2], e[3]);
  unsigned c = pk2(e[4], e[5]),   d  = pk2(e[6], e[7]);
  plswap(a, c);
  plswap(bq, d);
  u32x4 v0 = {a, bq, c, d};
  f0 = __builtin_bit_cast(bf16x8, v0);
  unsigned ee = pk2(e[8], e[9]),  ff = pk2(e[10], e[11]);
  unsigned g  = pk2(e[12], e[13]), h = pk2(e[14], e[15]);
  plswap(ee, g);
  plswap(ff, h);
  u32x4 v1 = {ee, ff, g, h};
  f1 = __builtin_bit_cast(bf16x8, v1);
}

// ---------------------------------------------------------------------------
// Swizzled LDS tiles: logical [rows][64] bf16, elem (r,c) at
//   r*64 + ((c>>3 ^ (r&7))<<3) + (c&7)
// -> 16B-aligned b128 reads AND conflict-free banks without padding.
// ---------------------------------------------------------------------------
__device__ __forceinline__ bf16x8 ldfrag(const u16* base, int row, int kb) {
  return *(const bf16x8*)(base + (row << 6) + ((kb ^ (row & 7)) << 3));
}
__device__ __forceinline__ void stage16(u16* dst, const u16* src, int c, int spitch) {
  const int r = c >> 3, cb = c & 7;
  const int4 v = *(const int4*)(src + (size_t)r * spitch + (cb << 3));
  *(int4*)(dst + (r << 6) + ((cb ^ (r & 7)) << 3)) = v;
}
// hoisted-staging helpers: LDS offset and global offset for chunk index c
__device__ __forceinline__ int soff_l(int c) {
  const int r = c >> 3, cb = c & 7;
  return (r << 6) + ((cb ^ (r & 7)) << 3);
}
__device__ __forceinline__ int soff_g(int c, int spitch) {
  return (c >> 3) * spitch + ((c & 7) << 3);
}

// ---------------------------------------------------------------------------
// Kernel 1: qkv projection + LayerNorm -> bf16. q pre-scaled by QSCALE.
// v written transposed vt[b][i][f] for the out kernel's B-fragments.
// ---------------------------------------------------------------------------
__global__ __launch_bounds__(256) void qkv_ln_k(
    const float* __restrict__ x,
    const float* __restrict__ Wq, const float* __restrict__ Wk,
    const float* __restrict__ Wv,
    u16* __restrict__ qn, u16* __restrict__ kn, u16* __restrict__ vt) {
  __shared__ float sW[3 * D_ * I_];
  __shared__ float xs[D_ * 64];
  __shared__ __align__(16) u16 vtile[64 * 72];

  const int t = threadIdx.x;
  const int b = blockIdx.y;
  const int f0 = blockIdx.x * 64;

  for (int i = t; i < D_ * I_; i += 256) {
    sW[i]               = Wq[i];
    sW[D_ * I_ + i]     = Wk[i];
    sW[2 * D_ * I_ + i] = Wv[i];
  }
  const float* xb = x + (size_t)b * D_ * F_ + f0;
  for (int i = t; i < D_ * 64; i += 256)
    xs[i] = xb[(size_t)(i >> 6) * F_ + (i & 63)];
  __syncthreads();

  const int lane = t & 63, w = t >> 6;

  for (int it = 0; it < 16; ++it) {
    const int fl = w * 16 + it;
    float hq = 0.f, hk = 0.f, hv = 0.f;
#pragma unroll
    for (int d = 0; d < D_; ++d) {
      const float xv = xs[d * 64 + fl];
      hq = fmaf(xv, sW[d * 64 + lane], hq);
      hk = fmaf(xv, sW[D_ * I_ + d * 64 + lane], hk);
      hv = fmaf(xv, sW[2 * D_ * I_ + d * 64 + lane], hv);
    }
    auto lnorm = [&](float a) -> float {
      float s = a;
#pragma unroll
      for (int o = 32; o > 0; o >>= 1) s += __shfl_xor(s, o, 64);
      const float mu = s * (1.f / 64.f);
      const float d0 = a - mu;
      float v = d0 * d0;
#pragma unroll
      for (int o = 32; o > 0; o >>= 1) v += __shfl_xor(v, o, 64);
      return d0 * rsqrtf(v * (1.f / 64.f) + EPS);
    };
    const size_t fo = ((size_t)b * F_ + f0 + fl) * I_ + lane;
    qn[fo] = f2b(lnorm(hq) * QSCALE);
    kn[fo] = f2b(lnorm(hk));
    vtile[lane * 72 + fl] = f2b(lnorm(hv));
  }
  __syncthreads();
  for (int p = 0; p < 2; ++p) {
    const int c = p * 256 + t;
    const int r = c >> 3, off = (c & 7) * 8;
    const int4 v = *(const int4*)&vtile[r * 72 + off];
    *(int4*)(vt + ((size_t)b * I_ + r) * F_ + f0 + off) = v;
  }
}

// ---------------------------------------------------------------------------
// Kernel 2: partial column-softmax sums zp[qh][b][k] = sum_{q in half} exp2(S).
// 256 thr / 4 waves, (256-k tile, b, q-half). K tile (32 KB) staged once ->
// each wave hoists its 64 k rows as B-fragments -> LDS reused as
// double-buffered Q stream with hoisted staging offsets. 1 barrier/chunk.
// ---------------------------------------------------------------------------
__global__ __launch_bounds__(256, 2) void attn_stats_k(
    const u16* __restrict__ qn, const u16* __restrict__ kn,
    float* __restrict__ zp) {
  __shared__ __align__(16) u16 sm[16384];   // 32 KB

  const int t = threadIdx.x, lane = t & 63, w = t >> 6;
  const int l31 = lane & 31, lh = lane >> 5;
  const int b = blockIdx.y, k0 = blockIdx.x * 256, qh = blockIdx.z;

  // stage K 256x64 (2048 chunks, 8/thread), hoist own 64-k B-fragments
  const u16* kb = kn + ((size_t)b * F_ + k0) * I_;
#pragma unroll
  for (int p = 0; p < 8; ++p) stage16(sm, kb, p * 256 + t, 64);
  __syncthreads();
  bf16x8 kf[2][4];
#pragma unroll
  for (int kb2 = 0; kb2 < 2; ++kb2)
#pragma unroll
    for (int ic = 0; ic < 4; ++ic)
      kf[kb2][ic] = ldfrag(sm + (w * 64 + kb2 * 32) * 64, l31, ic * 2 + lh);
  __syncthreads();                          // frag reads done before reuse

  // hoisted Q staging offsets (2 chunks16B per thread per 64-q chunk)
  int qoff_l[2], qoff_g[2];
#pragma unroll
  for (int p = 0; p < 2; ++p) {
    const int c = p * 256 + t;
    qoff_l[p] = soff_l(c);
    qoff_g[p] = soff_g(c, 64);
  }

  const u16* qsrc = qn + ((size_t)b * F_ + qh * (F_ / NQS)) * I_;
#pragma unroll
  for (int p = 0; p < 2; ++p)               // chunk 0 into buffer 0
    *(int4*)(sm + qoff_l[p]) = *(const int4*)(qsrc + qoff_g[p]);
  qsrc += 64 * I_;

  float Zc[2][2] = {{0.f, 0.f}, {0.f, 0.f}};  // [qb][kb]
  const int NC = F_ / NQS / 64;             // 32 chunks

  for (int c = 0; c < NC; ++c) {
    const int cur = (c & 1) * 4096;
    __syncthreads();                        // cur staged; nxt's old readers done
    if (c + 1 < NC) {
      const int nxt = cur ^ 4096;
#pragma unroll
      for (int p = 0; p < 2; ++p)
        *(int4*)(sm + nxt + qoff_l[p]) = *(const int4*)(qsrc + qoff_g[p]);
      qsrc += 64 * I_;
    }

    f32x16 a00 = ZERO16, a01 = ZERO16, a10 = ZERO16, a11 = ZERO16;
#pragma unroll
    for (int ic = 0; ic < 4; ++ic) {
      const bf16x8 q0f = ldfrag(sm + cur, l31, ic * 2 + lh);
      const bf16x8 q1f = ldfrag(sm + cur + 32 * 64, l31, ic * 2 + lh);
      a00 = MFMA32(q0f, kf[0][ic], a00);
      a01 = MFMA32(q0f, kf[1][ic], a01);
      a10 = MFMA32(q1f, kf[0][ic], a10);
      a11 = MFMA32(q1f, kf[1][ic], a11);
    }
#pragma unroll
    for (int r = 0; r < 16; ++r) {
      Zc[0][0] += EX2(a00[r]);
      Zc[0][1] += EX2(a01[r]);
      Zc[1][0] += EX2(a10[r]);
      Zc[1][1] += EX2(a11[r]);
    }
  }

#pragma unroll
  for (int kb2 = 0; kb2 < 2; ++kb2) {
    float Zt = Zc[0][kb2] + Zc[1][kb2];
    Zt += __shfl_xor(Zt, 32, 64);
    if (lane < 32)
      zp[((size_t)qh * B_ + b) * F_ + k0 + w * 64 + kb2 * 32 + lane] = Zt;
  }
}

// ---------------------------------------------------------------------------
// Kernel 3: fold 1/Z_k into V rows, in place: vt[b][i][k] *= 1/(zp0+zp1)[b][k].
// ---------------------------------------------------------------------------
__global__ __launch_bounds__(256) void vscale_k(u16* __restrict__ vt,
                                                const float* __restrict__ zp) {
  const int b = blockIdx.y;
  const int off = (blockIdx.x * 256 + (int)threadIdx.x) * 8;  // within I_*F_
  const int k = off & (F_ - 1);
  u16* p = vt + (size_t)b * I_ * F_ + off;
  const float* z0 = zp + (size_t)b * F_ + k;
  const float* z1 = zp + (size_t)B_ * F_ + (size_t)b * F_ + k;
  int4 raw = *(const int4*)p;
  u16 es[8], os[8];
  *(int4*)es = raw;
#pragma unroll
  for (int j = 0; j < 8; ++j) {
    const float v = __builtin_bit_cast(float, (unsigned)es[j] << 16);
    const float rz = RCP(z0[j] + z1[j]);
    os[j] = f2b(v * rz);
  }
  *(int4*)p = *(int4*)os;
}

// ---------------------------------------------------------------------------
// Kernel 4: out[q,i] = sum_k exp2(S_qk) * v'[k,i] over FULL k (v' pre-scaled
// by 1/Z). 128 thr / 2 waves, (128-q tile, b); each wave owns 64 q (8 hoisted
// Q B-fragments). Per 64-k chunk: S^T (A=K, 16 MFMA) -> exp2 + in-register
// transpose (permlane) -> 4 A-frag sets -> PV (16 MFMA). K/VT double-buffered
// with hoisted staging offsets; 1 barrier/chunk; no k-split, no reduce pass.
// LDS (u16 idx): K dbuf @ 0/4096, VT dbuf @ 8192/12288; Q staged @0 prologue.
// ---------------------------------------------------------------------------
__global__ __launch_bounds__(128, 2) void attn_out_k(
    const u16* __restrict__ qn, const u16* __restrict__ kn,
    const u16* __restrict__ vt, float* __restrict__ out) {
  __shared__ __align__(16) u16 sm[16384];   // 32 KB

  const int t = threadIdx.x, lane = t & 63, w = t >> 6;
  const int l31 = lane & 31, lh = lane >> 5;
  const int b = blockIdx.y, q0 = blockIdx.x * 128;

  // stage Q 128x64 (1024 chunks, 8/thread), hoist own 64-q B-fragments
  const u16* qb = qn + ((size_t)b * F_ + q0) * I_;
#pragma unroll
  for (int p = 0; p < 8; ++p) stage16(sm, qb, p * 128 + t, 64);
  __syncthreads();
  bf16x8 qf[2][4];
#pragma unroll
  for (int qb2 = 0; qb2 < 2; ++qb2)
#pragma unroll
    for (int ic = 0; ic < 4; ++ic)
      qf[qb2][ic] = ldfrag(sm + (w * 64 + qb2 * 32) * 64, l31, ic * 2 + lh);
  __syncthreads();                          // frag reads done before overwrite

  // hoisted staging offsets (4 K + 4 V chunks16B per thread per 64-k chunk)
  int off_l[4], kg[4], vg[4];
#pragma unroll
  for (int p = 0; p < 4; ++p) {
    const int c = p * 128 + t;
    off_l[p] = soff_l(c);
    kg[p] = soff_g(c, 64);
    vg[p] = soff_g(c, F_);
  }

  const u16* ksrc = kn + (size_t)b * F_ * I_;
  const u16* vsrc = vt + (size_t)b * I_ * F_;
  // stage chunk 0 into buffers 0
#pragma unroll
  for (int p = 0; p < 4; ++p) {
    *(int4*)(sm + off_l[p])        = *(const int4*)(ksrc + kg[p]);
    *(int4*)(sm + 8192 + off_l[p]) = *(const int4*)(vsrc + vg[p]);
  }
  ksrc += 64 * I_;
  vsrc += 64;

  f32x16 o00 = ZERO16, o01 = ZERO16, o10 = ZERO16, o11 = ZERO16; // [qb][ih]
  const int NC = F_ / 64;                   // 64 chunks

  for (int c = 0; c < NC; ++c) {
    const int cur = (c & 1) * 4096;
    __syncthreads();                        // buf[cur] staged; old readers done
    if (c + 1 < NC) {
      const int nxt = cur ^ 4096;
#pragma unroll
      for (int p = 0; p < 4; ++p) {
        *(int4*)(sm + nxt + off_l[p])        = *(const int4*)(ksrc + kg[p]);
        *(int4*)(sm + 8192 + nxt + off_l[p]) = *(const int4*)(vsrc + vg[p]);
      }
      ksrc += 64 * I_;
      vsrc += 64;
    }

    // S^T = K x Q(own 64q): rows=k (2 halves), cols=q (2 blocks)
    const u16* Kc = sm + cur;
    f32x16 s00 = ZERO16, s01 = ZERO16, s10 = ZERO16, s11 = ZERO16; // [kh][qb]
#pragma unroll
    for (int ic = 0; ic < 4; ++ic) {
      const bf16x8 ak0 = ldfrag(Kc, l31, ic * 2 + lh);
      const bf16x8 ak1 = ldfrag(Kc + 32 * 64, l31, ic * 2 + lh);
      s00 = MFMA32(ak0, qf[0][ic], s00);
      s01 = MFMA32(ak0, qf[1][ic], s01);
      s10 = MFMA32(ak1, qf[0][ic], s10);
      s11 = MFMA32(ak1, qf[1][ic], s11);
    }

    // exp2 + in-register transpose into PV A-fragments per q-block
    bf16x8 af[2][4];
    build_af(s00, af[0][0], af[0][1]);
    build_af(s10, af[0][2], af[0][3]);
    build_af(s01, af[1][0], af[1][1]);
    build_af(s11, af[1][2], af[1][3]);

    // O += P(64q x 64k) * V'(64k x 64i), two i-halves
    const u16* Vc = sm + 8192 + cur;
#pragma unroll
    for (int kb4 = 0; kb4 < 4; ++kb4) {
      const bf16x8 bv0 = ldfrag(Vc, l31, kb4 * 2 + lh);
      const bf16x8 bv1 = ldfrag(Vc + 32 * 64, l31, kb4 * 2 + lh);
      o00 = MFMA32(af[0][kb4], bv0, o00);
      o01 = MFMA32(af[0][kb4], bv1, o01);
      o10 = MFMA32(af[1][kb4], bv0, o10);
      o11 = MFMA32(af[1][kb4], bv1, o11);
    }
  }

  float* ob = out + ((size_t)b * F_ + q0 + w * 64) * I_;
#pragma unroll
  for (int r = 0; r < 16; ++r) {
    const int qr = (r & 3) + 8 * (r >> 2) + 4 * lh;   // C/D row mapping
    ob[(size_t)qr * I_ + l31]              = o00[r];
    ob[(size_t)qr * I_ + 32 + l31]         = o01[r];
    ob[(size_t)(32 + qr) * I_ + l31]       = o10[r];
    ob[(size_t)(32 + qr) * I_ + 32 + l31]  = o11[r];
  }
}

// ---------------------------------------------------------------------------
extern "C" void kernel_launch(void* const* d_in, const int* in_sizes, int n_in,
                              void* d_out, int out_size, void* d_ws,
                              size_t ws_size, hipStream_t stream) {
  const float* x  = (const float*)d_in[0];
  const float* Wq = (const float*)d_in[1];
  const float* Wk = (const float*)d_in[2];
  const float* Wv = (const float*)d_in[3];
  float* out = (float*)d_out;

  // workspace: qn, kn, vt (bf16, B*F*I each); zp (f32 [NQS][B][F])
  const size_t NBF = (size_t)B_ * F_ * I_;
  u16* qn   = (u16*)d_ws;
  u16* kn   = qn + NBF;
  u16* vt   = kn + NBF;
  float* zp = (float*)(vt + NBF);

  qkv_ln_k<<<dim3(F_ / 64, B_), 256, 0, stream>>>(x, Wq, Wk, Wv, qn, kn, vt);
  attn_stats_k<<<dim3(F_ / 256, B_, NQS), 256, 0, stream>>>(qn, kn, zp);
  vscale_k<<<dim3(I_ * F_ / 2048, B_), 256, 0, stream>>>(vt, zp);
  attn_out_k<<<dim3(F_ / 128, B_), 128, 0, stream>>>(qn, kn, vt, out);
}

// Round 7
// 241.769 us; speedup vs baseline: 1.1313x; 1.1313x over previous
//
#include <hip/hip_runtime.h>
#include <math.h>

// Problem constants (fixed-shape problem)
#define B_  16
#define D_  37
#define F_  4096
#define I_  64
#define EPS 1e-5f
// softmax scale 1/sqrt(64) folded with log2(e) into q at projection time,
// so S_mfma = att*log2e and softmax is a raw exp2. |att|<=8 (LN rows have
// norm exactly 8) -> exp2(S) <= 2^11.6: no max pass, bf16-safe unnormalized P.
#define QSCALE 0.18033688011112042f
#define NQS 2           // stats q-split (partial-Z planes)

typedef unsigned short u16;
typedef __bf16 bf16x8 __attribute__((ext_vector_type(8)));
typedef __bf16 bf16x2v __attribute__((ext_vector_type(2)));
typedef float  f32x16 __attribute__((ext_vector_type(16)));
typedef float  f32x2v __attribute__((ext_vector_type(2)));
typedef unsigned int u32x4 __attribute__((ext_vector_type(4)));
typedef int i32x2 __attribute__((ext_vector_type(2)));

#define ZERO16 {0,0,0,0, 0,0,0,0, 0,0,0,0, 0,0,0,0}
#define MFMA32(a, b, c) __builtin_amdgcn_mfma_f32_32x32x16_bf16((a), (b), (c), 0, 0, 0)

#if __has_builtin(__builtin_amdgcn_exp2f)
#define EX2(x) __builtin_amdgcn_exp2f(x)
#else
#define EX2(x) exp2f(x)
#endif
#if __has_builtin(__builtin_amdgcn_rcpf)
#define RCP(x) __builtin_amdgcn_rcpf(x)
#else
#define RCP(x) (1.f / (x))
#endif

// fp32 -> bf16 RNE (scalar)
__device__ __forceinline__ u16 f2b(float f) {
  unsigned u = __builtin_bit_cast(unsigned, f);
  return (u16)((u + 0x7fffu + ((u >> 16) & 1u)) >> 16);
}
// bf16 bits -> fp32
__device__ __forceinline__ float b2f(u16 h) {
  return __builtin_bit_cast(float, (unsigned)h << 16);
}
// pack two fp32 -> bf16x2 (one v_cvt_pk_bf16_f32 where available)
__device__ __forceinline__ unsigned pk2(float lo, float hi) {
  f32x2v f = {lo, hi};
  bf16x2v h = __builtin_convertvector(f, bf16x2v);
  return __builtin_bit_cast(unsigned, h);
}

// half-wave register swap (v_permlane32_swap_b32 on gfx950)
__device__ __forceinline__ void plswap(unsigned& a, unsigned& b) {
#if __has_builtin(__builtin_amdgcn_permlane32_swap)
  i32x2 r = __builtin_amdgcn_permlane32_swap((int)a, (int)b, false, false);
  a = (unsigned)r[0];
  b = (unsigned)r[1];
#else
  const int lh = (int)((threadIdx.x & 63) >> 5);
  unsigned pa = (unsigned)__shfl_xor((int)a, 32, 64);
  unsigned pb = (unsigned)__shfl_xor((int)b, 32, 64);
  unsigned na = lh ? pb : a;
  unsigned nb = lh ? b : pa;
  a = na;
  b = nb;
#endif
}

// From one S^T 32x32 C-block (rows=k, cols=q), build two PV A-fragments
// (m=q, contraction k): f0 = k 0..15, f1 = k 16..31 of this block.
// C-reg r holds k=(r&3)+8*(r>>2)+4*lh; A-frag VGPR j needs k=lh*8+2j(+1).
__device__ __forceinline__ void build_af(const f32x16& s, bf16x8& f0, bf16x8& f1) {
  float e[16];
#pragma unroll
  for (int r = 0; r < 16; ++r) e[r] = EX2(s[r]);
  unsigned a = pk2(e[0], e[1]),   bq = pk2(e[2], e[3]);
  unsigned c = pk2(e[4], e[5]),   d  = pk2(e[6], e[7]);
  plswap(a, c);
  plswap(bq, d);
  u32x4 v0 = {a, bq, c, d};
  f0 = __builtin_bit_cast(bf16x8, v0);
  unsigned ee = pk2(e[8], e[9]),  ff = pk2(e[10], e[11]);
  unsigned g  = pk2(e[12], e[13]), h = pk2(e[14], e[15]);
  plswap(ee, g);
  plswap(ff, h);
  u32x4 v1 = {ee, ff, g, h};
  f1 = __builtin_bit_cast(bf16x8, v1);
}

// ---------------------------------------------------------------------------
// Swizzled LDS tiles: logical [rows][64] bf16, elem (r,c) at
//   r*64 + ((c>>3 ^ (r&7))<<3) + (c&7)
// -> 16B-aligned b128 reads AND conflict-free banks without padding.
// ---------------------------------------------------------------------------
__device__ __forceinline__ bf16x8 ldfrag(const u16* base, int row, int kb) {
  return *(const bf16x8*)(base + (row << 6) + ((kb ^ (row & 7)) << 3));
}
__device__ __forceinline__ void stage16(u16* dst, const u16* src, int c, int spitch) {
  const int r = c >> 3, cb = c & 7;
  const int4 v = *(const int4*)(src + (size_t)r * spitch + (cb << 3));
  *(int4*)(dst + (r << 6) + ((cb ^ (r & 7)) << 3)) = v;
}
// hoisted-staging helpers: LDS offset and global offset for chunk index c
__device__ __forceinline__ int soff_l(int c) {
  const int r = c >> 3, cb = c & 7;
  return (r << 6) + ((cb ^ (r & 7)) << 3);
}
__device__ __forceinline__ int soff_g(int c, int spitch) {
  return (c >> 3) * spitch + ((c & 7) << 3);
}

// ---------------------------------------------------------------------------
// Kernel 1: qkv projection + LayerNorm -> bf16. q pre-scaled by QSCALE.
// v written transposed vt[b][i][f] for the out kernel's B-fragments.
// ---------------------------------------------------------------------------
__global__ __launch_bounds__(256) void qkv_ln_k(
    const float* __restrict__ x,
    const float* __restrict__ Wq, const float* __restrict__ Wk,
    const float* __restrict__ Wv,
    u16* __restrict__ qn, u16* __restrict__ kn, u16* __restrict__ vt) {
  __shared__ float sW[3 * D_ * I_];
  __shared__ float xs[D_ * 64];
  __shared__ __align__(16) u16 vtile[64 * 72];

  const int t = threadIdx.x;
  const int b = blockIdx.y;
  const int f0 = blockIdx.x * 64;

  for (int i = t; i < D_ * I_; i += 256) {
    sW[i]               = Wq[i];
    sW[D_ * I_ + i]     = Wk[i];
    sW[2 * D_ * I_ + i] = Wv[i];
  }
  const float* xb = x + (size_t)b * D_ * F_ + f0;
  for (int i = t; i < D_ * 64; i += 256)
    xs[i] = xb[(size_t)(i >> 6) * F_ + (i & 63)];
  __syncthreads();

  const int lane = t & 63, w = t >> 6;

  for (int it = 0; it < 16; ++it) {
    const int fl = w * 16 + it;
    float hq = 0.f, hk = 0.f, hv = 0.f;
#pragma unroll
    for (int d = 0; d < D_; ++d) {
      const float xv = xs[d * 64 + fl];
      hq = fmaf(xv, sW[d * 64 + lane], hq);
      hk = fmaf(xv, sW[D_ * I_ + d * 64 + lane], hk);
      hv = fmaf(xv, sW[2 * D_ * I_ + d * 64 + lane], hv);
    }
    auto lnorm = [&](float a) -> float {
      float s = a;
#pragma unroll
      for (int o = 32; o > 0; o >>= 1) s += __shfl_xor(s, o, 64);
      const float mu = s * (1.f / 64.f);
      const float d0 = a - mu;
      float v = d0 * d0;
#pragma unroll
      for (int o = 32; o > 0; o >>= 1) v += __shfl_xor(v, o, 64);
      return d0 * rsqrtf(v * (1.f / 64.f) + EPS);
    };
    const size_t fo = ((size_t)b * F_ + f0 + fl) * I_ + lane;
    qn[fo] = f2b(lnorm(hq) * QSCALE);
    kn[fo] = f2b(lnorm(hk));
    vtile[lane * 72 + fl] = f2b(lnorm(hv));
  }
  __syncthreads();
  for (int p = 0; p < 2; ++p) {
    const int c = p * 256 + t;
    const int r = c >> 3, off = (c & 7) * 8;
    const int4 v = *(const int4*)&vtile[r * 72 + off];
    *(int4*)(vt + ((size_t)b * I_ + r) * F_ + f0 + off) = v;
  }
}

// ---------------------------------------------------------------------------
// Kernel 2: partial column-softmax sums zp[qh][b][k] = sum_{q in half} exp2(S).
// 256 thr / 4 waves, (256-k tile, b, q-half). K tile (32 KB) staged once ->
// each wave hoists its 64 k rows as B-fragments -> LDS reused as
// double-buffered Q stream with hoisted staging offsets. 1 barrier/chunk.
// ---------------------------------------------------------------------------
__global__ __launch_bounds__(256, 2) void attn_stats_k(
    const u16* __restrict__ qn, const u16* __restrict__ kn,
    float* __restrict__ zp) {
  __shared__ __align__(16) u16 sm[16384];   // 32 KB

  const int t = threadIdx.x, lane = t & 63, w = t >> 6;
  const int l31 = lane & 31, lh = lane >> 5;
  const int b = blockIdx.y, k0 = blockIdx.x * 256, qh = blockIdx.z;

  // stage K 256x64 (2048 chunks, 8/thread), hoist own 64-k B-fragments
  const u16* kb = kn + ((size_t)b * F_ + k0) * I_;
#pragma unroll
  for (int p = 0; p < 8; ++p) stage16(sm, kb, p * 256 + t, 64);
  __syncthreads();
  bf16x8 kf[2][4];
#pragma unroll
  for (int kb2 = 0; kb2 < 2; ++kb2)
#pragma unroll
    for (int ic = 0; ic < 4; ++ic)
      kf[kb2][ic] = ldfrag(sm + (w * 64 + kb2 * 32) * 64, l31, ic * 2 + lh);
  __syncthreads();                          // frag reads done before reuse

  // hoisted Q staging offsets (2 chunks16B per thread per 64-q chunk)
  int qoff_l[2], qoff_g[2];
#pragma unroll
  for (int p = 0; p < 2; ++p) {
    const int c = p * 256 + t;
    qoff_l[p] = soff_l(c);
    qoff_g[p] = soff_g(c, 64);
  }

  const u16* qsrc = qn + ((size_t)b * F_ + qh * (F_ / NQS)) * I_;
#pragma unroll
  for (int p = 0; p < 2; ++p)               // chunk 0 into buffer 0
    *(int4*)(sm + qoff_l[p]) = *(const int4*)(qsrc + qoff_g[p]);
  qsrc += 64 * I_;

  float Zc[2][2] = {{0.f, 0.f}, {0.f, 0.f}};  // [qb][kb]
  const int NC = F_ / NQS / 64;             // 32 chunks

  for (int c = 0; c < NC; ++c) {
    const int cur = (c & 1) * 4096;
    __syncthreads();                        // cur staged; nxt's old readers done
    if (c + 1 < NC) {
      const int nxt = cur ^ 4096;
#pragma unroll
      for (int p = 0; p < 2; ++p)
        *(int4*)(sm + nxt + qoff_l[p]) = *(const int4*)(qsrc + qoff_g[p]);
      qsrc += 64 * I_;
    }

    f32x16 a00 = ZERO16, a01 = ZERO16, a10 = ZERO16, a11 = ZERO16;
#pragma unroll
    for (int ic = 0; ic < 4; ++ic) {
      const bf16x8 q0f = ldfrag(sm + cur, l31, ic * 2 + lh);
      const bf16x8 q1f = ldfrag(sm + cur + 32 * 64, l31, ic * 2 + lh);
      a00 = MFMA32(q0f, kf[0][ic], a00);
      a01 = MFMA32(q0f, kf[1][ic], a01);
      a10 = MFMA32(q1f, kf[0][ic], a10);
      a11 = MFMA32(q1f, kf[1][ic], a11);
    }
#pragma unroll
    for (int r = 0; r < 16; ++r) {
      Zc[0][0] += EX2(a00[r]);
      Zc[0][1] += EX2(a01[r]);
      Zc[1][0] += EX2(a10[r]);
      Zc[1][1] += EX2(a11[r]);
    }
  }

#pragma unroll
  for (int kb2 = 0; kb2 < 2; ++kb2) {
    float Zt = Zc[0][kb2] + Zc[1][kb2];
    Zt += __shfl_xor(Zt, 32, 64);
    if (lane < 32)
      zp[((size_t)qh * B_ + b) * F_ + k0 + w * 64 + kb2 * 32 + lane] = Zt;
  }
}

// ---------------------------------------------------------------------------
// Kernel 3: fold 1/Z_k into V rows, in place: vt[b][i][k] *= 1/(zp0+zp1)[b][k].
// ---------------------------------------------------------------------------
__global__ __launch_bounds__(256) void vscale_k(u16* __restrict__ vt,
                                                const float* __restrict__ zp) {
  const int b = blockIdx.y;
  const int off = (blockIdx.x * 256 + (int)threadIdx.x) * 8;  // within I_*F_
  const int k = off & (F_ - 1);
  u16* p = vt + (size_t)b * I_ * F_ + off;
  const float* z0 = zp + (size_t)b * F_ + k;
  const float* z1 = zp + (size_t)B_ * F_ + (size_t)b * F_ + k;
  int4 raw = *(const int4*)p;
  u16 es[8], os[8];
  *(int4*)es = raw;
#pragma unroll
  for (int j = 0; j < 8; ++j) {
    const float v = b2f(es[j]);
    const float rz = RCP(z0[j] + z1[j]);
    os[j] = f2b(v * rz);
  }
  *(int4*)p = *(int4*)os;
}

// ---------------------------------------------------------------------------
// Kernel 4: partial out over a k-half: out[q,i] = sum_{k in half} exp2(S)*v'.
// 128 thr / 2 waves, (128-q tile, b, k-split); each wave owns 64 q (8 hoisted
// Q B-fragments). Per 64-k chunk: S^T (A=K, 16 MFMA) -> exp2 + in-register
// transpose (permlane) -> PV (16 MFMA). K/VT double-buffered, hoisted staging
// offsets, 1 barrier/chunk. 32 KB LDS -> 4 blocks/CU (8 waves, 4 barrier
// domains). ks=0 -> fp32 out; ks=1 -> bf16 partial (reduce_k folds).
// ---------------------------------------------------------------------------
__global__ __launch_bounds__(128, 2) void attn_out_k(
    const u16* __restrict__ qn, const u16* __restrict__ kn,
    const u16* __restrict__ vt, float* __restrict__ out,
    u16* __restrict__ pout) {
  __shared__ __align__(16) u16 sm[16384];   // 32 KB

  const int t = threadIdx.x, lane = t & 63, w = t >> 6;
  const int l31 = lane & 31, lh = lane >> 5;
  const int b = blockIdx.y, q0 = blockIdx.x * 128, ks = blockIdx.z;

  // stage Q 128x64 (1024 chunks, 8/thread), hoist own 64-q B-fragments
  const u16* qb = qn + ((size_t)b * F_ + q0) * I_;
#pragma unroll
  for (int p = 0; p < 8; ++p) stage16(sm, qb, p * 128 + t, 64);
  __syncthreads();
  bf16x8 qf[2][4];
#pragma unroll
  for (int qb2 = 0; qb2 < 2; ++qb2)
#pragma unroll
    for (int ic = 0; ic < 4; ++ic)
      qf[qb2][ic] = ldfrag(sm + (w * 64 + qb2 * 32) * 64, l31, ic * 2 + lh);
  __syncthreads();                          // frag reads done before overwrite

  // hoisted staging offsets (4 K + 4 V chunks16B per thread per 64-k chunk)
  int off_l[4], kg[4], vg[4];
#pragma unroll
  for (int p = 0; p < 4; ++p) {
    const int c = p * 128 + t;
    off_l[p] = soff_l(c);
    kg[p] = soff_g(c, 64);
    vg[p] = soff_g(c, F_);
  }

  const u16* ksrc = kn + ((size_t)b * F_ + ks * (F_ / 2)) * I_;
  const u16* vsrc = vt + (size_t)b * I_ * F_ + ks * (F_ / 2);
  // stage chunk 0 into buffers 0
#pragma unroll
  for (int p = 0; p < 4; ++p) {
    *(int4*)(sm + off_l[p])        = *(const int4*)(ksrc + kg[p]);
    *(int4*)(sm + 8192 + off_l[p]) = *(const int4*)(vsrc + vg[p]);
  }
  ksrc += 64 * I_;
  vsrc += 64;

  f32x16 o00 = ZERO16, o01 = ZERO16, o10 = ZERO16, o11 = ZERO16; // [qb][ih]
  const int NC = F_ / 2 / 64;               // 32 chunks in this k-half

  for (int c = 0; c < NC; ++c) {
    const int cur = (c & 1) * 4096;
    __syncthreads();                        // buf[cur] staged; old readers done
    if (c + 1 < NC) {
      const int nxt = cur ^ 4096;
#pragma unroll
      for (int p = 0; p < 4; ++p) {
        *(int4*)(sm + nxt + off_l[p])        = *(const int4*)(ksrc + kg[p]);
        *(int4*)(sm + 8192 + nxt + off_l[p]) = *(const int4*)(vsrc + vg[p]);
      }
      ksrc += 64 * I_;
      vsrc += 64;
    }

    // S^T = K x Q(own 64q): rows=k (2 halves), cols=q (2 blocks)
    const u16* Kc = sm + cur;
    f32x16 s00 = ZERO16, s01 = ZERO16, s10 = ZERO16, s11 = ZERO16; // [kh][qb]
#pragma unroll
    for (int ic = 0; ic < 4; ++ic) {
      const bf16x8 ak0 = ldfrag(Kc, l31, ic * 2 + lh);
      const bf16x8 ak1 = ldfrag(Kc + 32 * 64, l31, ic * 2 + lh);
      s00 = MFMA32(ak0, qf[0][ic], s00);
      s01 = MFMA32(ak0, qf[1][ic], s01);
      s10 = MFMA32(ak1, qf[0][ic], s10);
      s11 = MFMA32(ak1, qf[1][ic], s11);
    }

    // exp2 + in-register transpose into PV A-fragments per q-block
    bf16x8 af[2][4];
    build_af(s00, af[0][0], af[0][1]);
    build_af(s10, af[0][2], af[0][3]);
    build_af(s01, af[1][0], af[1][1]);
    build_af(s11, af[1][2], af[1][3]);

    // O += P(64q x 64k) * V'(64k x 64i), two i-halves
    const u16* Vc = sm + 8192 + cur;
#pragma unroll
    for (int kb4 = 0; kb4 < 4; ++kb4) {
      const bf16x8 bv0 = ldfrag(Vc, l31, kb4 * 2 + lh);
      const bf16x8 bv1 = ldfrag(Vc + 32 * 64, l31, kb4 * 2 + lh);
      o00 = MFMA32(af[0][kb4], bv0, o00);
      o01 = MFMA32(af[0][kb4], bv1, o01);
      o10 = MFMA32(af[1][kb4], bv0, o10);
      o11 = MFMA32(af[1][kb4], bv1, o11);
    }
  }

  if (ks == 0) {
    float* ob = out + ((size_t)b * F_ + q0 + w * 64) * I_;
#pragma unroll
    for (int r = 0; r < 16; ++r) {
      const int qr = (r & 3) + 8 * (r >> 2) + 4 * lh;   // C/D row mapping
      ob[(size_t)qr * I_ + l31]              = o00[r];
      ob[(size_t)qr * I_ + 32 + l31]         = o01[r];
      ob[(size_t)(32 + qr) * I_ + l31]       = o10[r];
      ob[(size_t)(32 + qr) * I_ + 32 + l31]  = o11[r];
    }
  } else {
    u16* pb = pout + ((size_t)b * F_ + q0 + w * 64) * I_;
#pragma unroll
    for (int r = 0; r < 16; ++r) {
      const int qr = (r & 3) + 8 * (r >> 2) + 4 * lh;
      pb[(size_t)qr * I_ + l31]              = f2b(o00[r]);
      pb[(size_t)qr * I_ + 32 + l31]         = f2b(o01[r]);
      pb[(size_t)(32 + qr) * I_ + l31]       = f2b(o10[r]);
      pb[(size_t)(32 + qr) * I_ + 32 + l31]  = f2b(o11[r]);
    }
  }
}

// ---------------------------------------------------------------------------
// Kernel 5: out += bf16 partial (k-split reduction). 8 elems/thread.
// ---------------------------------------------------------------------------
__global__ __launch_bounds__(256) void reduce_k(float* __restrict__ out,
                                                const u16* __restrict__ pout) {
  const size_t i = ((size_t)blockIdx.x * 256 + threadIdx.x) * 8;
  float4 a0 = *(const float4*)(out + i);
  float4 a1 = *(const float4*)(out + i + 4);
  int4 praw = *(const int4*)(pout + i);
  u16 es[8];
  *(int4*)es = praw;
  a0.x += b2f(es[0]); a0.y += b2f(es[1]); a0.z += b2f(es[2]); a0.w += b2f(es[3]);
  a1.x += b2f(es[4]); a1.y += b2f(es[5]); a1.z += b2f(es[6]); a1.w += b2f(es[7]);
  *(float4*)(out + i)     = a0;
  *(float4*)(out + i + 4) = a1;
}

// ---------------------------------------------------------------------------
extern "C" void kernel_launch(void* const* d_in, const int* in_sizes, int n_in,
                              void* d_out, int out_size, void* d_ws,
                              size_t ws_size, hipStream_t stream) {
  const float* x  = (const float*)d_in[0];
  const float* Wq = (const float*)d_in[1];
  const float* Wk = (const float*)d_in[2];
  const float* Wv = (const float*)d_in[3];
  float* out = (float*)d_out;

  // workspace: qn, kn, vt (bf16, B*F*I each); zp (f32 [NQS][B][F]);
  //            pout (bf16 [B][F][I] k-split partial)
  const size_t NBF = (size_t)B_ * F_ * I_;
  u16* qn   = (u16*)d_ws;
  u16* kn   = qn + NBF;
  u16* vt   = kn + NBF;
  float* zp = (float*)(vt + NBF);
  u16* pout = (u16*)(zp + (size_t)NQS * B_ * F_);

  qkv_ln_k<<<dim3(F_ / 64, B_), 256, 0, stream>>>(x, Wq, Wk, Wv, qn, kn, vt);
  attn_stats_k<<<dim3(F_ / 256, B_, NQS), 256, 0, stream>>>(qn, kn, zp);
  vscale_k<<<dim3(I_ * F_ / 2048, B_), 256, 0, stream>>>(vt, zp);
  attn_out_k<<<dim3(F_ / 128, B_, 2), 128, 0, stream>>>(qn, kn, vt, out, pout);
  reduce_k<<<dim3((int)(NBF / 2048)), 256, 0, stream>>>(out, pout);
}